// Round 2
// baseline (23734.183 us; speedup 1.0000x reference)
//
#include <hip/hip_runtime.h>

// Problem constants: B=512 T=512 I=128 H=512 C=128 OUT_T=128
#define Tq 512
#define Iq 128
#define Hq 512
#define Cq 128
#define OUT_Tq 128

#define KS_E 20   // encoder k-steps: 640/32  (k<128 -> W_ih, else W_hh)
#define KS_H 16   // 512/32
#define NT_H 32   // 512/16 n-tiles
#define NT_C 8    // 128/16

// ---- ws byte offsets (all 16B aligned) ----
#define SZ_WE   (NT_H * KS_E * 64 * 8 * 2)   // 655360
#define SZ_W1   (NT_H * KS_H * 64 * 8 * 2)   // 524288
#define SZ_W2   (NT_C * KS_H * 64 * 8 * 2)   // 131072
#define OFF_WEH 0
#define OFF_WEL (OFF_WEH + SZ_WE)
#define OFF_W1H (OFF_WEL + SZ_WE)
#define OFF_W1L (OFF_W1H + SZ_W1)
#define OFF_W2H (OFF_W1L + SZ_W1)
#define OFF_W2L (OFF_W2H + SZ_W2)
#define OFF_CB  (OFF_W2L + SZ_W2)            // 2621440, 2048 bytes

typedef short s16x8 __attribute__((ext_vector_type(8)));
typedef float f32x4 __attribute__((ext_vector_type(4)));

union U8 { uint4 q; s16x8 v; ushort u[8]; };

__device__ __forceinline__ ushort f2bf(float f) {
    union { float f; unsigned u; } a; a.f = f;
    unsigned u = a.u;
    unsigned r = (u + 0x7FFFu + ((u >> 16) & 1u)) >> 16;   // RNE
    return (ushort)r;
}
__device__ __forceinline__ float bf2f(ushort h) {
    union { unsigned u; float f; } a; a.u = ((unsigned)h) << 16;
    return a.f;
}

// ---------------- weight prep: fp32 -> split-bf16 B-fragment layout ----------------
// frag elem index: (((n>>4)*KS + (k>>5))*64 + ((k>>3)&3)*16 + (n&15))*8 + (k&7)

__global__ void prep_enc(const float* __restrict__ W_ih, const float* __restrict__ W_hh,
                         ushort* __restrict__ Wh, ushort* __restrict__ Wl) {
    int idx = blockIdx.x * 256 + threadIdx.x;            // over 512*640
    if (idx >= 512 * 640) return;
    int n = idx / 640, k = idx % 640;
    float v = (k < Iq) ? W_ih[n * Iq + k] : W_hh[n * Hq + (k - Iq)];
    ushort hi = f2bf(v); ushort lo = f2bf(v - bf2f(hi));
    int dst = (((n >> 4) * KS_E + (k >> 5)) * 64 + ((k >> 3) & 3) * 16 + (n & 15)) * 8 + (k & 7);
    Wh[dst] = hi; Wl[dst] = lo;
}

__global__ void prep_fc1(const float* __restrict__ W, ushort* __restrict__ Wh,
                         ushort* __restrict__ Wl) {
    int idx = blockIdx.x * 256 + threadIdx.x;            // over 512*512
    if (idx >= 512 * 512) return;
    int n = idx >> 9, k = idx & 511;
    float v = W[n * Hq + k];
    ushort hi = f2bf(v); ushort lo = f2bf(v - bf2f(hi));
    int dst = (((n >> 4) * KS_H + (k >> 5)) * 64 + ((k >> 3) & 3) * 16 + (n & 15)) * 8 + (k & 7);
    Wh[dst] = hi; Wl[dst] = lo;
}

__global__ void prep_fc2(const float* __restrict__ W, ushort* __restrict__ Wh,
                         ushort* __restrict__ Wl) {
    int idx = blockIdx.x * 256 + threadIdx.x;            // over 128*512
    if (idx >= 128 * 512) return;
    int n = idx >> 9, k = idx & 511;
    float v = W[n * Hq + k];
    ushort hi = f2bf(v); ushort lo = f2bf(v - bf2f(hi));
    int dst = (((n >> 4) * KS_H + (k >> 5)) * 64 + ((k >> 3) & 3) * 16 + (n & 15)) * 8 + (k & 7);
    Wh[dst] = hi; Wl[dst] = lo;
}

__global__ void prep_cb(const float* __restrict__ bih, const float* __restrict__ bhh,
                        float* __restrict__ cb) {
    int n = blockIdx.x * 256 + threadIdx.x;
    if (n < Hq) cb[n] = bih[n] + bhh[n];
}

// ---------------- fused persistent RNN ----------------
// 32 blocks x 512 threads (8 waves). Block g owns batches [g*16, g*16+16).
// Activations in LDS as split-bf16 A-frags: elem (m,k) -> ((k>>5)*64 + ((k>>3)&3)*16 + m)*8 + (k&7)
// enc storage k: [0,128)=x_t, [128,640)=h.  mid (decoder) single-bf16, k=n in [0,512).

__global__ void __launch_bounds__(512)
rnn_mfma(const float* __restrict__ x, const int* __restrict__ lengths,
         const ushort* __restrict__ WEh, const ushort* __restrict__ WEl,
         const ushort* __restrict__ W1h, const ushort* __restrict__ W1l,
         const ushort* __restrict__ W2h, const ushort* __restrict__ W2l,
         const float* __restrict__ cb, const float* __restrict__ fc1_b,
         const float* __restrict__ fc2_b, float* __restrict__ out) {
    __shared__ ushort Ah[KS_E * 512];   // 20480 B
    __shared__ ushort Al[KS_E * 512];   // 20480 B
    __shared__ ushort Mh[KS_H * 512];   // 16384 B
    __shared__ int sLen[16];

    const int tid = threadIdx.x;
    const int w = tid >> 6, lane = tid & 63;
    const int qd = lane >> 4, nlo = lane & 15;
    const int g = blockIdx.x;

    if (tid < 16) sLen[tid] = lengths[g * 16 + tid];
    // zero h region (zero everything; x region overwritten each step)
    {
        uint4 z = make_uint4(0, 0, 0, 0);
        for (int i = tid; i < KS_E * 64; i += 512) {
            ((uint4*)Ah)[i] = z;
            ((uint4*)Al)[i] = z;
        }
    }
    __syncthreads();

    int lenv[4], tmax = 0;
#pragma unroll
    for (int r = 0; r < 4; ++r) lenv[r] = sLen[qd * 4 + r];
    for (int i = 0; i < 16; ++i) tmax = max(tmax, sLen[i]);

    float cbv[4], f1bv[4];
#pragma unroll
    for (int i = 0; i < 4; ++i) {
        int n = (w * 4 + i) * 16 + nlo;
        cbv[i] = cb[n];
        f1bv[i] = fc1_b[n];
    }
    const float f2bv = fc2_b[w * 16 + nlo];

    const f32x4 fz = {0.f, 0.f, 0.f, 0.f};

    // ---------------- encoder ----------------
    for (int t = 0; t < tmax; ++t) {
        {   // stage x_t as split A-frags (ks 0..3)
            int m = tid >> 5, i4 = (tid & 31) << 2;
            const float4 xv = *(const float4*)&x[((size_t)(g * 16 + m) * Tq + t) * Iq + i4];
            ushort4 h4, l4;
            float v;
            v = xv.x; h4.x = f2bf(v); l4.x = f2bf(v - bf2f(h4.x));
            v = xv.y; h4.y = f2bf(v); l4.y = f2bf(v - bf2f(h4.y));
            v = xv.z; h4.z = f2bf(v); l4.z = f2bf(v - bf2f(h4.z));
            v = xv.w; h4.w = f2bf(v); l4.w = f2bf(v - bf2f(h4.w));
            int base = ((i4 >> 5) * 64 + ((i4 >> 3) & 3) * 16 + m) * 8 + (i4 & 7);
            *(ushort4*)&Ah[base] = h4;
            *(ushort4*)&Al[base] = l4;
        }
        __syncthreads();   // E1: x + prev-h visible

        f32x4 acc[4] = {fz, fz, fz, fz};
        for (int ks = 0; ks < KS_E; ++ks) {
            U8 a_h, a_l;
            a_h.q = *(const uint4*)&Ah[(ks * 64 + lane) * 8];
            a_l.q = *(const uint4*)&Al[(ks * 64 + lane) * 8];
#pragma unroll
            for (int i = 0; i < 4; ++i) {
                int nt = w * 4 + i;
                U8 b_h, b_l;
                b_h.q = *(const uint4*)&WEh[((nt * KS_E + ks) * 64 + lane) * 8];
                b_l.q = *(const uint4*)&WEl[((nt * KS_E + ks) * 64 + lane) * 8];
                acc[i] = __builtin_amdgcn_mfma_f32_16x16x32_bf16(a_h.v, b_h.v, acc[i], 0, 0, 0);
                acc[i] = __builtin_amdgcn_mfma_f32_16x16x32_bf16(a_h.v, b_l.v, acc[i], 0, 0, 0);
                acc[i] = __builtin_amdgcn_mfma_f32_16x16x32_bf16(a_l.v, b_h.v, acc[i], 0, 0, 0);
            }
        }
        __syncthreads();   // E2: all A reads done

        // epilogue: h_new = tanh(acc + cb), masked write into A-frag h region
#pragma unroll
        for (int i = 0; i < 4; ++i) {
            int n = (w * 4 + i) * 16 + nlo;
            int k = 128 + n;
            int base = ((k >> 5) * 64 + ((k >> 3) & 3) * 16) * 8 + (k & 7);
#pragma unroll
            for (int r = 0; r < 4; ++r) {
                int m = qd * 4 + r;
                float v = tanhf(acc[i][r] + cbv[i]);
                ushort hi = f2bf(v), lo = f2bf(v - bf2f(hi));
                if (t < lenv[r]) {   // frozen batches keep old split-h
                    Ah[base + m * 8] = hi;
                    Al[base + m * 8] = lo;
                }
            }
        }
        // next xStage writes ks0..3 (disjoint from epilogue); E1 publishes both
    }

    // ---------------- decoder ----------------
    for (int t = 0; t < OUT_Tq; ++t) {
        __syncthreads();   // S1
        // nh = tanh(cb + h @ W_hh^T)  (B-frags = enc weights at ks 4..19)
        f32x4 acc[4] = {fz, fz, fz, fz};
        for (int ks = 0; ks < KS_H; ++ks) {
            U8 a_h, a_l;
            a_h.q = *(const uint4*)&Ah[((ks + 4) * 64 + lane) * 8];
            a_l.q = *(const uint4*)&Al[((ks + 4) * 64 + lane) * 8];
#pragma unroll
            for (int i = 0; i < 4; ++i) {
                int nt = w * 4 + i;
                U8 b_h, b_l;
                b_h.q = *(const uint4*)&WEh[((nt * KS_E + ks + 4) * 64 + lane) * 8];
                b_l.q = *(const uint4*)&WEl[((nt * KS_E + ks + 4) * 64 + lane) * 8];
                acc[i] = __builtin_amdgcn_mfma_f32_16x16x32_bf16(a_h.v, b_h.v, acc[i], 0, 0, 0);
                acc[i] = __builtin_amdgcn_mfma_f32_16x16x32_bf16(a_h.v, b_l.v, acc[i], 0, 0, 0);
                acc[i] = __builtin_amdgcn_mfma_f32_16x16x32_bf16(a_l.v, b_h.v, acc[i], 0, 0, 0);
            }
        }
        __syncthreads();   // S2
#pragma unroll
        for (int i = 0; i < 4; ++i) {
            int n = (w * 4 + i) * 16 + nlo;
            int k = 128 + n;
            int base = ((k >> 5) * 64 + ((k >> 3) & 3) * 16) * 8 + (k & 7);
#pragma unroll
            for (int r = 0; r < 4; ++r) {
                int m = qd * 4 + r;
                float v = tanhf(acc[i][r] + cbv[i]);
                ushort hi = f2bf(v), lo = f2bf(v - bf2f(hi));
                Ah[base + m * 8] = hi;
                Al[base + m * 8] = lo;
            }
        }
        __syncthreads();   // S3
        // mid = relu(nh @ fc1^T + b)
        f32x4 accm[4] = {fz, fz, fz, fz};
        for (int ks = 0; ks < KS_H; ++ks) {
            U8 a_h, a_l;
            a_h.q = *(const uint4*)&Ah[((ks + 4) * 64 + lane) * 8];
            a_l.q = *(const uint4*)&Al[((ks + 4) * 64 + lane) * 8];
#pragma unroll
            for (int i = 0; i < 4; ++i) {
                int nt = w * 4 + i;
                U8 b_h, b_l;
                b_h.q = *(const uint4*)&W1h[((nt * KS_H + ks) * 64 + lane) * 8];
                b_l.q = *(const uint4*)&W1l[((nt * KS_H + ks) * 64 + lane) * 8];
                accm[i] = __builtin_amdgcn_mfma_f32_16x16x32_bf16(a_h.v, b_h.v, accm[i], 0, 0, 0);
                accm[i] = __builtin_amdgcn_mfma_f32_16x16x32_bf16(a_h.v, b_l.v, accm[i], 0, 0, 0);
                accm[i] = __builtin_amdgcn_mfma_f32_16x16x32_bf16(a_l.v, b_h.v, accm[i], 0, 0, 0);
            }
        }
        __syncthreads();   // S4
#pragma unroll
        for (int i = 0; i < 4; ++i) {
            int n = (w * 4 + i) * 16 + nlo;     // mid index = out-GEMM k
            int base = ((n >> 5) * 64 + ((n >> 3) & 3) * 16) * 8 + (n & 7);
#pragma unroll
            for (int r = 0; r < 4; ++r) {
                int m = qd * 4 + r;
                float v = fmaxf(accm[i][r] + f1bv[i], 0.f);
                Mh[base + m * 8] = f2bf(v);     // single bf16 (head tolerance)
            }
        }
        __syncthreads();   // S5
        // out = mid @ fc2^T + b   (wave w -> c-tile w; 2-term: mid single-bf16)
        f32x4 acco = fz;
        for (int ks = 0; ks < KS_H; ++ks) {
            U8 a_m, b_h, b_l;
            a_m.q = *(const uint4*)&Mh[(ks * 64 + lane) * 8];
            b_h.q = *(const uint4*)&W2h[((w * KS_H + ks) * 64 + lane) * 8];
            b_l.q = *(const uint4*)&W2l[((w * KS_H + ks) * 64 + lane) * 8];
            acco = __builtin_amdgcn_mfma_f32_16x16x32_bf16(a_m.v, b_h.v, acco, 0, 0, 0);
            acco = __builtin_amdgcn_mfma_f32_16x16x32_bf16(a_m.v, b_l.v, acco, 0, 0, 0);
        }
        {
            int c = w * 16 + nlo;
#pragma unroll
            for (int r = 0; r < 4; ++r) {
                int bglob = g * 16 + qd * 4 + r;
                out[((size_t)bglob * OUT_Tq + t) * Cq + c] = acco[r] + f2bv;
            }
        }
    }
}

extern "C" void kernel_launch(void* const* d_in, const int* in_sizes, int n_in,
                              void* d_out, int out_size, void* d_ws, size_t ws_size,
                              hipStream_t stream) {
    const float* x     = (const float*)d_in[0];
    const int*   lens  = (const int*)d_in[1];
    // d_in[2] = out_lengths (constant 128)
    const float* W_ih  = (const float*)d_in[3];
    const float* W_hh  = (const float*)d_in[4];
    const float* b_ih  = (const float*)d_in[5];
    const float* b_hh  = (const float*)d_in[6];
    const float* fc1_W = (const float*)d_in[7];
    const float* fc1_b = (const float*)d_in[8];
    const float* fc2_W = (const float*)d_in[9];
    const float* fc2_b = (const float*)d_in[10];

    char* ws = (char*)d_ws;
    ushort* WEh = (ushort*)(ws + OFF_WEH);
    ushort* WEl = (ushort*)(ws + OFF_WEL);
    ushort* W1h = (ushort*)(ws + OFF_W1H);
    ushort* W1l = (ushort*)(ws + OFF_W1L);
    ushort* W2h = (ushort*)(ws + OFF_W2H);
    ushort* W2l = (ushort*)(ws + OFF_W2L);
    float*  cbp = (float*)(ws + OFF_CB);

    prep_enc<<<1280, 256, 0, stream>>>(W_ih, W_hh, WEh, WEl);
    prep_fc1<<<1024, 256, 0, stream>>>(fc1_W, W1h, W1l);
    prep_fc2<<< 256, 256, 0, stream>>>(fc2_W, W2h, W2l);
    prep_cb <<<   2, 256, 0, stream>>>(b_ih, b_hh, cbp);

    rnn_mfma<<<32, 512, 0, stream>>>(x, lens, WEh, WEl, W1h, W1l, W2h, W2l,
                                     cbp, fc1_b, fc2_b, (float*)d_out);
}